// Round 7
// baseline (633.309 us; speedup 1.0000x reference)
//
#include <hip/hip_runtime.h>
#include <hip/hip_bf16.h>

typedef __attribute__((ext_vector_type(8))) short short8;
typedef __attribute__((ext_vector_type(4))) float floatx4;

#define NQ 512
#define NH 100000
#define DM 256
#define BQ 128
#define WSTR 56   // w_lds row stride (ushort); 112B rows keep 16B alignment

#define MFMA_BF16(a, b, c) __builtin_amdgcn_mfma_f32_16x16x32_bf16((a), (b), (c), 0, 0, 0)
#define SCHED0 __builtin_amdgcn_sched_barrier(0)

#define PIPE_BAR(N) do {                                      \
    asm volatile("s_waitcnt vmcnt(" #N ")" ::: "memory");     \
    __builtin_amdgcn_sched_barrier(0);                        \
    __builtin_amdgcn_s_barrier();                             \
    __builtin_amdgcn_sched_barrier(0);                        \
} while (0)

__device__ __forceinline__ unsigned short f2bf(float f) {
    __hip_bfloat16 h = __float2bfloat16(f);            // RNE, native cvt path
    union { __hip_bfloat16 h; unsigned short u; } v; v.h = h;
    return v.u;
}

// f32-element XOR swizzle (16B granularity + 64B bit): rows spread 2-way on banks
__device__ __forceinline__ int swz4f(int r) { return (4 * (r & 7)) ^ (16 * ((r >> 3) & 1)); }

__device__ __forceinline__ void gload_lds16(const float* g, float* l) {
    __builtin_amdgcn_global_load_lds((const __attribute__((address_space(1))) void*)g,
                                     (__attribute__((address_space(3))) void*)l,
                                     16, 0, 0);
}

// ---- stage one 16-row K/V half-tile pair async into LDS (zero registers) ----
// waves 0-3: K rows 4*(wid&3).. ; waves 4-7: V rows. 4 ops/wave (vmcnt).
__device__ __forceinline__ void issue_stage(const float* __restrict__ Kg,
                                            const float* __restrict__ Vg,
                                            long hb, int wid, int lane,
                                            float* Kbuf, float* Vbuf)
{
    const bool isK = (wid < 4);
    const int r0 = (wid & 3) * 4;
    const float* src = isK ? Kg : Vg;
    float* dst = isK ? Kbuf : Vbuf;
#pragma unroll
    for (int rr = 0; rr < 4; ++rr) {
        const int r = r0 + rr;
        long grow = hb + r; if (grow > (long)NH - 1) grow = (long)NH - 1;
        const float* gp = src + (size_t)grow * DM + ((4 * lane) ^ swz4f(r));
        gload_lds16(gp, dst + r * DM);
    }
}

// ---- mask for one half-tile in S C-frag layout: col h=l15, row q=4g+jj (4 ops) ----
__device__ __forceinline__ void issue_mask(const float* __restrict__ Mg,
                                           long hb, int qrow0, int g, int l15, float* m)
{
    long h = hb + l15; if (h > (long)NH - 1) h = (long)NH - 1;
#pragma unroll
    for (int jj = 0; jj < 4; ++jj)
        m[jj] = Mg[(size_t)(qrow0 + 4 * g + jj) * NH + h];
}

// ---- S = Q K^T (16q x 16h), K read f32-swizzled + cvt ----
__device__ __forceinline__ floatx4 compute_S(const float* Kc, const short8* qa, int g, int l15)
{
    const int sw = swz4f(l15);
    const float* kr = Kc + l15 * DM;
    floatx4 sf = {0.f, 0.f, 0.f, 0.f};
#pragma unroll
    for (int ks = 0; ks < 8; ++ks) {
        const int c0 = (32 * ks + 8 * g) ^ sw;
        const int c1 = (32 * ks + 8 * g + 4) ^ sw;
        floatx4 a0 = *(const floatx4*)(kr + c0);
        floatx4 a1 = *(const floatx4*)(kr + c1);
        short8 kb;
        kb[0]=(short)f2bf(a0[0]); kb[1]=(short)f2bf(a0[1]);
        kb[2]=(short)f2bf(a0[2]); kb[3]=(short)f2bf(a0[3]);
        kb[4]=(short)f2bf(a1[0]); kb[5]=(short)f2bf(a1[1]);
        kb[6]=(short)f2bf(a1[2]); kb[7]=(short)f2bf(a1[3]);
        sf = MFMA_BF16(qa[ks], kb, sf);
    }
    return sf;
}

// ---- w = mask*exp(s/16); store into wave-private w_lds rows (bank-XOR'd cols) ----
__device__ __forceinline__ void do_w(floatx4 sf, const float* m, long hbase, long hEnd,
                                     int wid, int g, int l15, int half01,
                                     unsigned short* w_lds, float* dacc)
{
    const bool valid = (hbase + l15) < hEnd;
#pragma unroll
    for (int jj = 0; jj < 4; ++jj) {
        float mm = valid ? m[jj] : 0.f;
        float s = sf[jj] * 0.0625f;
        s = (s > 60.f) ? 60.f : s;
        float w = mm * __expf(s);
        dacc[jj] += w;
        const int q = 16 * wid + 4 * g + jj;
        w_lds[q * WSTR + ((half01 * 16 + l15) ^ (8 * g))] = f2bf(w);
    }
}

// ---- PV over a 32-h pair: acc[fd] += w(16q x 32h) * V(32h x 16d) ----
// A-fragment rows are THIS WAVE's q rows: w_lds row = 16*wid + l15.
__device__ __forceinline__ void do_pv(const float* Ve, const float* Vo,
                                      const unsigned short* w_lds,
                                      int wid, int g, int l15, floatx4* acc)
{
    const float* Vsel = (g & 2) ? Vo : Ve;
    const int rbase = 8 * (g & 1);
    short8 wa = *(const short8*)&w_lds[(16 * wid + l15) * WSTR + 8 * (g ^ (l15 >> 2))];
#pragma unroll
    for (int fd = 0; fd < 16; ++fd) {
        short8 vb;
#pragma unroll
        for (int i = 0; i < 8; ++i) {
            const int r = rbase + i;
            vb[i] = (short)f2bf(Vsel[r * DM + ((16 * fd + l15) ^ swz4f(r))]);
        }
        acc[fd] = MFMA_BF16(wa, vb, acc[fd]);
    }
}

__global__ __launch_bounds__(512, 2)
void maskattn_phase1(const float* __restrict__ Qg,
                     const float* __restrict__ Kg,
                     const float* __restrict__ Vg,
                     const float* __restrict__ Mg,
                     float* __restrict__ numW,
                     float* __restrict__ denW,
                     int CH)
{
    __shared__ __attribute__((aligned(16))) float K_lds[4][16 * DM];           // 64 KB
    __shared__ __attribute__((aligned(16))) float V_lds[4][16 * DM];           // 64 KB
    __shared__ __attribute__((aligned(16))) unsigned short w_lds[BQ * WSTR];   // 14 KB (wave-private rows)

    const int tid  = threadIdx.x;
    const int lane = tid & 63;
    const int wid  = tid >> 6;     // 0..7, owns q rows 16*wid..+15
    const int g    = lane >> 4;    // 0..3
    const int l15  = lane & 15;

    const int qt    = blockIdx.x & 3;
    const int hc    = blockIdx.x >> 2;
    const int qbase = qt * BQ;
    const long h0   = (long)hc * CH;
    const long hEnd = (h0 + CH < (long)NH) ? (h0 + CH) : (long)NH;
    const int qrow0 = qbase + 16 * wid;

    // ---- Q fragments: A[row=l15][k=8g+i], k-chunk ks: d = 32*ks + 8*g + i ----
    short8 qa[8];
    {
        const float* qp = Qg + (size_t)(qrow0 + l15) * DM + 8 * g;
#pragma unroll
        for (int ks = 0; ks < 8; ++ks) {
            floatx4 a = *(const floatx4*)(qp + 32 * ks);
            floatx4 b = *(const floatx4*)(qp + 32 * ks + 4);
            short8 fr;
            fr[0]=(short)f2bf(a[0]); fr[1]=(short)f2bf(a[1]);
            fr[2]=(short)f2bf(a[2]); fr[3]=(short)f2bf(a[3]);
            fr[4]=(short)f2bf(b[0]); fr[5]=(short)f2bf(b[1]);
            fr[6]=(short)f2bf(b[2]); fr[7]=(short)f2bf(b[3]);
            qa[ks] = fr;
        }
    }

    floatx4 acc[16];
#pragma unroll
    for (int i = 0; i < 16; ++i) { floatx4 z = {0.f,0.f,0.f,0.f}; acc[i] = z; }
    float dacc[4] = {0.f, 0.f, 0.f, 0.f};

    int nvalid = (int)(hEnd - h0); if (nvalid < 0) nvalid = 0;
    const int nIter = (nvalid + 63) >> 6;          // 4 half-tiles (64 h) per iteration

    if (nIter > 0) {
        float m0[4], m1[4], m2[4], m3[4];

        // ---- prologue: batches 0,1 (each its own sched region = 8 VMEM ops) ----
        SCHED0;
        issue_mask(Mg, h0,      qrow0, g, l15, m0);
        issue_stage(Kg, Vg, h0,      wid, lane, K_lds[0], V_lds[0]);
        SCHED0;
        issue_mask(Mg, h0 + 16, qrow0, g, l15, m1);
        issue_stage(Kg, Vg, h0 + 16, wid, lane, K_lds[1], V_lds[1]);
        SCHED0;
        PIPE_BAR(8);   // batch0 arrived; batch1 in flight

        for (int it = 0; it < nIter; ++it) {
            const long jb = h0 + (long)it * 64;

            // ---- half A (buf0, m0): issue batches ->bufs 2,3 ----
            SCHED0;
            issue_mask(Mg, jb + 32, qrow0, g, l15, m2);
            issue_stage(Kg, Vg, jb + 32, wid, lane, K_lds[2], V_lds[2]);
            SCHED0;
            issue_mask(Mg, jb + 48, qrow0, g, l15, m3);
            issue_stage(Kg, Vg, jb + 48, wid, lane, K_lds[3], V_lds[3]);
            SCHED0;
            { floatx4 sf = compute_S(K_lds[0], qa, g, l15);
              do_w(sf, m0, jb,      hEnd, wid, g, l15, 0, w_lds, dacc); }
            PIPE_BAR(16);  // buf1 ready; 2 batches still flying

            // ---- half B (buf1, m1) + PV(0,1) ----
            { floatx4 sf = compute_S(K_lds[1], qa, g, l15);
              do_w(sf, m1, jb + 16, hEnd, wid, g, l15, 1, w_lds, dacc); }
            do_pv(V_lds[0], V_lds[1], w_lds, wid, g, l15, acc);
            PIPE_BAR(8);   // buf2 ready; 1 batch flying

            // ---- half C (buf2, m2): issue batches ->bufs 0,1 ----
            SCHED0;
            issue_mask(Mg, jb + 64, qrow0, g, l15, m0);
            issue_stage(Kg, Vg, jb + 64, wid, lane, K_lds[0], V_lds[0]);
            SCHED0;
            issue_mask(Mg, jb + 80, qrow0, g, l15, m1);
            issue_stage(Kg, Vg, jb + 80, wid, lane, K_lds[1], V_lds[1]);
            SCHED0;
            { floatx4 sf = compute_S(K_lds[2], qa, g, l15);
              do_w(sf, m2, jb + 32, hEnd, wid, g, l15, 0, w_lds, dacc); }
            PIPE_BAR(16);  // buf3 ready

            // ---- half D (buf3, m3) + PV(2,3) ----
            { floatx4 sf = compute_S(K_lds[3], qa, g, l15);
              do_w(sf, m3, jb + 48, hEnd, wid, g, l15, 1, w_lds, dacc); }
            do_pv(V_lds[2], V_lds[3], w_lds, wid, g, l15, acc);
            PIPE_BAR(8);   // buf0 ready for next iteration
        }
    }

    // ---- den: sum over the 16 h-lanes of each row (waves own disjoint q) ----
#pragma unroll
    for (int jj = 0; jj < 4; ++jj) {
        float v = dacc[jj];
        v += __shfl_xor(v, 1);
        v += __shfl_xor(v, 2);
        v += __shfl_xor(v, 4);
        v += __shfl_xor(v, 8);
        if (l15 == 0)
            denW[(size_t)hc * NQ + qrow0 + 4 * g + jj] = v;
    }

    // ---- num partial write: q = qrow0 + 4g + jj, d = 16 fd + l15 ----
#pragma unroll
    for (int fd = 0; fd < 16; ++fd)
#pragma unroll
        for (int jj = 0; jj < 4; ++jj) {
            const int q = qrow0 + 4 * g + jj;
            const int d = 16 * fd + l15;
            numW[((size_t)hc * NQ + q) * DM + d] = acc[fd][jj];
        }
}

__global__ void maskattn_reduce(const float* __restrict__ numW,
                                const float* __restrict__ denW,
                                float* __restrict__ out, int C)
{
    const int q = blockIdx.x;
    const int d = threadIdx.x;
    float sn = 0.f, sd = 0.f;
    for (int c = 0; c < C; ++c) {
        sn += numW[((size_t)c * NQ + q) * DM + d];
        sd += denW[(size_t)c * NQ + q];
    }
    out[(size_t)q * DM + d] = sn / sd;
}

extern "C" void kernel_launch(void* const* d_in, const int* in_sizes, int n_in,
                              void* d_out, int out_size, void* d_ws, size_t ws_size,
                              hipStream_t stream)
{
    const float* Qg = (const float*)d_in[0];
    const float* Kg = (const float*)d_in[1];
    const float* Vg = (const float*)d_in[2];
    const float* Mg = (const float*)d_in[3];
    float* out = (float*)d_out;

    const size_t per_chunk = (size_t)NQ * DM * sizeof(float) + (size_t)NQ * sizeof(float);
    int C = (int)(ws_size / per_chunk);
    if (C > 64) C = 64;
    float* numW;
    float* denW;
    if (C >= 1) {
        numW = (float*)d_ws;
        denW = numW + (size_t)C * NQ * DM;
    } else {
        C = 1;
        numW = out;                  // emergency fallback
        denW = (float*)d_ws;
    }
    const int CH = 16 * ((NH + 16 * C - 1) / (16 * C));

    maskattn_phase1<<<dim3((NQ / BQ) * C), dim3(512), 0, stream>>>(Qg, Kg, Vg, Mg, numW, denW, CH);
    maskattn_reduce<<<dim3(NQ), dim3(DM), 0, stream>>>(numW, denW, out, C);
}

// Round 8
// 623.540 us; speedup vs baseline: 1.0157x; 1.0157x over previous
//
#include <hip/hip_runtime.h>
#include <hip/hip_bf16.h>

typedef __attribute__((ext_vector_type(8))) short short8;
typedef __attribute__((ext_vector_type(4))) float floatx4;

#define NQ 512
#define NH 100000
#define DM 256
#define BH 32
#define BQ 256
#define VTSTR 40   // V^T row stride (ushort): 80 B -> 16B-aligned, 20-bank step
#define MWSTR 36   // mask/w row stride (f32): 144 B -> 16B-aligned, 4-bank step

#define MFMA_BF16(a,b,c) __builtin_amdgcn_mfma_f32_16x16x32_bf16((a),(b),(c),0,0,0)

__device__ __forceinline__ unsigned short f2bf(float f){
    union{float f;unsigned u;}v;v.f=f;
    unsigned u=v.u+0x7fffu+((v.u>>16)&1u);   // RNE
    return (unsigned short)(u>>16);
}
__device__ __forceinline__ float bf2f(unsigned short s){
    union{unsigned u;float f;}v;v.u=((unsigned)s)<<16;return v.f;
}
// f32-element XOR swizzle for K rows (16B granularity + 64B bit)
__device__ __forceinline__ int swz4f(int r){ return (4*(r&7)) ^ (16*((r>>3)&1)); }

__device__ __forceinline__ void gload_lds16(const float* g, float* l){
    __builtin_amdgcn_global_load_lds((const __attribute__((address_space(1))) void*)g,
                                     (__attribute__((address_space(3))) void*)l, 16, 0, 0);
}

// waves 0..7 stage K rows 4w..4w+3 (1 KB row per inst, swizzled source)
__device__ __forceinline__ void stage_K(const float* __restrict__ Kg, long hb,
                                        int wid, int lane, float* Kbuf){
    if (wid < 8) {
#pragma unroll
        for (int rr = 0; rr < 4; ++rr) {
            const int r = (wid << 2) | rr;
            long grow = hb + r; if (grow > (long)NH - 1) grow = (long)NH - 1;
            gload_lds16(Kg + (size_t)grow * DM + ((4 * lane) ^ swz4f(r)), Kbuf + r * DM);
        }
    }
}
// waves 8..15 stage V rows (linear — consumed row-major by the transpose)
__device__ __forceinline__ void stage_V(const float* __restrict__ Vg, long hb,
                                        int wid, int lane, float* Vbuf){
    if (wid >= 8) {
#pragma unroll
        for (int rr = 0; rr < 4; ++rr) {
            const int r = ((wid - 8) << 2) | rr;
            long grow = hb + r; if (grow > (long)NH - 1) grow = (long)NH - 1;
            gload_lds16(Vg + (size_t)grow * DM + 4 * lane, Vbuf + r * DM);
        }
    }
}

__global__ __launch_bounds__(1024, 4)
void maskattn_phase1(const float* __restrict__ Qg, const float* __restrict__ Kg,
                     const float* __restrict__ Vg, const float* __restrict__ Mg,
                     unsigned short* __restrict__ numW, float* __restrict__ denW, int CH)
{
    __shared__ __attribute__((aligned(16))) float K_lds[2][BH * DM];          // 64 KB
    __shared__ __attribute__((aligned(16))) float V_lds[BH * DM];             // 32 KB
    __shared__ __attribute__((aligned(16))) unsigned short VT_lds[DM * VTSTR];// 20 KB
    __shared__ __attribute__((aligned(16))) float MW_lds[BQ * MWSTR];         // 36 KB

    const int tid = threadIdx.x, lane = tid & 63, wid = tid >> 6;  // wid 0..15: owns q rows 16*wid..+15
    const int g = lane >> 4, l15 = lane & 15;

    const int qt = blockIdx.x & 1;
    const int hc = blockIdx.x >> 1;
    const int qbase = qt * BQ;
    const long h0 = (long)hc * CH;
    const long hEnd = (h0 + CH < (long)NH) ? (h0 + CH) : (long)NH;
    const int qrow0 = qbase + 16 * wid;

    // ---- Q fragment: A[row=l15][k=8g+i], k-chunk ks -> d = 32*ks + 8*g + i ----
    short8 qa[8];
    {
        const float* qp = Qg + (size_t)(qrow0 + l15) * DM + 8 * g;
#pragma unroll
        for (int ks = 0; ks < 8; ++ks) {
            floatx4 a = *(const floatx4*)(qp + 32 * ks);
            floatx4 b = *(const floatx4*)(qp + 32 * ks + 4);
            short8 fr;
            fr[0]=(short)f2bf(a[0]); fr[1]=(short)f2bf(a[1]); fr[2]=(short)f2bf(a[2]); fr[3]=(short)f2bf(a[3]);
            fr[4]=(short)f2bf(b[0]); fr[5]=(short)f2bf(b[1]); fr[6]=(short)f2bf(b[2]); fr[7]=(short)f2bf(b[3]);
            qa[ks] = fr;
        }
    }

    floatx4 acc[16];
#pragma unroll
    for (int i = 0; i < 16; ++i) { floatx4 z = {0.f,0.f,0.f,0.f}; acc[i] = z; }
    float dacc[4] = {0.f, 0.f, 0.f, 0.f};

    int nv = (int)(hEnd - h0); if (nv < 0) nv = 0;
    const int nt = (nv + BH - 1) / BH;

    if (nt > 0) {
        stage_K(Kg, h0, wid, lane, K_lds[0]);
        stage_V(Vg, h0, wid, lane, V_lds);
        int cur = 0;

        for (int t = 0; t < nt; ++t) {
            const long hb = h0 + (long)t * BH;
            __syncthreads();   // B1: tile t staged (drain); VT free; K[cur^1] free

            // ---- mask(t): full-128B-line loads into regs (4 lanes cover one q row) ----
            floatx4 mv0, mv1;
            const int mrl = lane >> 2, ms0 = lane & 3;
            {
                const float* mp = Mg + (size_t)(qrow0 + mrl) * NH;
                long c0 = hb + 4 * ms0;      if (c0 > (long)NH - 4) c0 = (long)NH - 4;
                long c1 = hb + 4 * ms0 + 16; if (c1 > (long)NH - 4) c1 = (long)NH - 4;
                mv0 = *(const floatx4*)(mp + c0);
                mv1 = *(const floatx4*)(mp + c1);
            }
            if (t + 1 < nt) stage_K(Kg, hb + BH, wid, lane, K_lds[cur ^ 1]);

            // ---- S(t) = Q K^T : 16q x 32h per wave; K read f32-swizzled + cvt ----
            floatx4 sf[2];
            { floatx4 z = {0.f,0.f,0.f,0.f}; sf[0] = z; sf[1] = z; }
            const float* Kc = K_lds[cur];
#pragma unroll
            for (int hh = 0; hh < 2; ++hh) {
                const int krow = 16 * hh + l15;
                const float* kr = Kc + krow * DM;
                const int sw = swz4f(krow);
#pragma unroll
                for (int ks = 0; ks < 8; ++ks) {
                    const int x0 = (32 * ks + 8 * g) ^ sw;
                    floatx4 a0 = *(const floatx4*)(kr + x0);
                    floatx4 a1 = *(const floatx4*)(kr + (x0 ^ 4));
                    short8 kb;
                    kb[0]=(short)f2bf(a0[0]); kb[1]=(short)f2bf(a0[1]); kb[2]=(short)f2bf(a0[2]); kb[3]=(short)f2bf(a0[3]);
                    kb[4]=(short)f2bf(a1[0]); kb[5]=(short)f2bf(a1[1]); kb[6]=(short)f2bf(a1[2]); kb[7]=(short)f2bf(a1[3]);
                    sf[hh] = MFMA_BF16(qa[ks], kb, sf[hh]);
                }
            }

            // ---- commit mask to wave-private MW rows (vmcnt hidden under S) ----
            {
                float* mwp = &MW_lds[(16 * wid + mrl) * MWSTR + 4 * ms0];
                *(floatx4*)mwp = mv0;
                *(floatx4*)(mwp + 16) = mv1;
            }
            // ---- transpose V(t): f32 rows -> bf16 V^T[d][h] ----
            {
                const int tr = tid >> 5, tc0 = tid & 31;
#pragma unroll
                for (int i = 0; i < 8; ++i) {
                    const int c = tc0 + 32 * i;
                    VT_lds[c * VTSTR + tr] = f2bf(V_lds[tr * DM + c]);
                }
            }
            __syncthreads();   // B2: VT complete; V_lds free
            if (t + 1 < nt) stage_V(Vg, hb + BH, wid, lane, V_lds);

            // ---- w(t) = mask * exp(s/16), in place in MW (wave-private) ----
#pragma unroll
            for (int hh = 0; hh < 2; ++hh) {
                const bool valid = (hb + 16 * hh + l15) < hEnd;
#pragma unroll
                for (int jj = 0; jj < 4; ++jj) {
                    const int row = 16 * wid + 4 * g + jj;
                    float m = MW_lds[row * MWSTR + 16 * hh + l15];
                    float s = sf[hh][jj] * 0.0625f;
                    s = (s > 60.f) ? 60.f : s;
                    float w = valid ? (m * __expf(s)) : 0.f;
                    dacc[jj] += w;
                    MW_lds[row * MWSTR + 16 * hh + l15] = w;
                }
            }

            // ---- PV(t): acc[fd] += w(16q x 32h) * V^T(32h x 256d) ----
            {
                const float* wr = &MW_lds[(16 * wid + l15) * MWSTR + 8 * g];
                floatx4 w0 = *(const floatx4*)(wr);
                floatx4 w1 = *(const floatx4*)(wr + 4);
                short8 wa;
                wa[0]=(short)f2bf(w0[0]); wa[1]=(short)f2bf(w0[1]); wa[2]=(short)f2bf(w0[2]); wa[3]=(short)f2bf(w0[3]);
                wa[4]=(short)f2bf(w1[0]); wa[5]=(short)f2bf(w1[1]); wa[6]=(short)f2bf(w1[2]); wa[7]=(short)f2bf(w1[3]);
#pragma unroll
                for (int fd = 0; fd < 16; ++fd) {
                    short8 vb = *(const short8*)&VT_lds[(16 * fd + l15) * VTSTR + 8 * g];
                    acc[fd] = MFMA_BF16(wa, vb, acc[fd]);
                }
            }
            cur ^= 1;
        }
    }

    // ---- den: rows are wave-private -> shfl over 16 h-lanes, direct store ----
#pragma unroll
    for (int jj = 0; jj < 4; ++jj) {
        float v = dacc[jj];
        v += __shfl_xor(v, 1);
        v += __shfl_xor(v, 2);
        v += __shfl_xor(v, 4);
        v += __shfl_xor(v, 8);
        if (l15 == 0)
            denW[(size_t)hc * NQ + qbase + 16 * wid + 4 * g + jj] = v;
    }

    // ---- num partial (bf16): q = qbase+16wid+4g+jj, d = 16fd+l15 ----
#pragma unroll
    for (int fd = 0; fd < 16; ++fd)
#pragma unroll
        for (int jj = 0; jj < 4; ++jj) {
            const int q = qbase + 16 * wid + 4 * g + jj;
            numW[((size_t)hc * NQ + q) * DM + 16 * fd + l15] = f2bf(acc[fd][jj]);
        }
}

__global__ void maskattn_reduce(const unsigned short* __restrict__ numW,
                                const float* __restrict__ denW,
                                float* __restrict__ out, int C)
{
    const int q = blockIdx.x;
    const int d = threadIdx.x;
    float sn = 0.f, sd = 0.f;
    for (int c = 0; c < C; ++c) {
        sn += bf2f(numW[((size_t)c * NQ + q) * DM + d]);
        sd += denW[(size_t)c * NQ + q];
    }
    out[(size_t)q * DM + d] = sn / sd;
}

extern "C" void kernel_launch(void* const* d_in, const int* in_sizes, int n_in,
                              void* d_out, int out_size, void* d_ws, size_t ws_size,
                              hipStream_t stream)
{
    const float* Qg = (const float*)d_in[0];
    const float* Kg = (const float*)d_in[1];
    const float* Vg = (const float*)d_in[2];
    const float* Mg = (const float*)d_in[3];
    float* out = (float*)d_out;

    const size_t per_chunk = (size_t)NQ * DM * 2 + (size_t)NQ * 4;   // bf16 num + f32 den
    int C = (int)(ws_size / per_chunk);
    if (C > 128) C = 128;
    if (C < 1) C = 1;
    unsigned short* numW = (unsigned short*)d_ws;
    float* denW = (float*)((char*)d_ws + (size_t)C * NQ * DM * 2);

    const int CH = BH * (int)((NH + (long)BH * C - 1) / ((long)BH * C));

    maskattn_phase1<<<dim3(2 * C), dim3(1024), 0, stream>>>(Qg, Kg, Vg, Mg, numW, denW, CH);
    maskattn_reduce<<<dim3(NQ), dim3(DM), 0, stream>>>(numW, denW, out, C);
}